// Round 4
// baseline (3506.513 us; speedup 1.0000x reference)
//
#include <hip/hip_runtime.h>
#include <hip/hip_fp16.h>

// GCN 3-layer forward. R4: src-locality aggregation.
// R3 lesson: pulls pin at ~3.77 TB/s L2-miss BW (fabric/L3 random ceiling);
// uniform-random gathers fetch ~85B/edge with no reuse. Fix = manufacture
// locality: edges partitioned (dst-bucket of 512) x (src-super of 8192);
// edge-major aggregation with LDS accumulators, all 977 blocks co-resident
// sweeping src-supers in lockstep -> gathers hit a moving L2 window.
// B,C intermediates fp16 (B 16MB, C 4MB: C fully per-XCD-L2-resident).

typedef unsigned int uint;
typedef unsigned short ushort;

#define NB 1024           // dst buckets (dst>>9), 512 nodes each
#define NS 64             // src supers (src>>13), 8192 nodes each
#define PT1_THREADS 1024
#define PT2_THREADS 512
#define PT_TILE 8192

// ---- pass-1 histogram by dst-bucket ----
__global__ void k_hist(const int* __restrict__ dst, int E, uint* __restrict__ bcnt) {
    __shared__ uint h[NB];
    int t = threadIdx.x;
    for (int i = t; i < NB; i += 256) h[i] = 0;
    __syncthreads();
    for (long long e = (long long)blockIdx.x * 256 + t; e < E; e += (long long)gridDim.x * 256)
        atomicAdd(&h[((uint)dst[e]) >> 9], 1u);
    __syncthreads();
    for (int i = t; i < NB; i += 256) if (h[i]) atomicAdd(&bcnt[i], h[i]);
}

// single block, NB threads
__global__ void k_scan_buckets(const uint* __restrict__ bcnt, uint* __restrict__ bbase,
                               uint* __restrict__ gcur) {
    __shared__ uint s[NB];
    int t = threadIdx.x;
    uint v = bcnt[t];
    s[t] = v;
    __syncthreads();
    for (int off = 1; off < NB; off <<= 1) {
        uint x = (t >= off) ? s[t - off] : 0u;
        __syncthreads();
        s[t] += x;
        __syncthreads();
    }
    uint ex = s[t] - v;
    bbase[t] = ex;
    gcur[t] = ex;
    if (t == NB - 1) bbase[NB] = s[t];
}

// ---- pass-1 partition by dst-bucket; pack src(19b) | dstLocal(9b)<<19 ----
__global__ __launch_bounds__(PT1_THREADS) void k_part(const int* __restrict__ src,
        const int* __restrict__ dst, int E, uint* __restrict__ gcur,
        uint* __restrict__ packed1) {
    __shared__ uint stage[PT_TILE];
    __shared__ ushort sbuck[PT_TILE];
    __shared__ uint hist[NB], lofs[NB], base[NB];
    int t = threadIdx.x;
    long long start = (long long)blockIdx.x * PT_TILE;
    int cnt = (int)min((long long)PT_TILE, (long long)E - start);
    hist[t] = 0;
    __syncthreads();
    uint myb[8], myr[8], mys[8];
#pragma unroll
    for (int k = 0; k < 8; ++k) {
        int idx = t + k * PT1_THREADS;
        if (idx < cnt) {
            uint dd = (uint)dst[start + idx];
            uint ss = (uint)src[start + idx];
            uint b = dd >> 9;
            myb[k] = b;
            mys[k] = ss | ((dd & 511u) << 19);
            myr[k] = atomicAdd(&hist[b], 1u);
        }
    }
    __syncthreads();
    uint v = hist[t];
    lofs[t] = v;
    __syncthreads();
    for (int off = 1; off < NB; off <<= 1) {
        uint x = (t >= off) ? lofs[t - off] : 0u;
        __syncthreads();
        lofs[t] += x;
        __syncthreads();
    }
    uint ex = lofs[t] - v;
    __syncthreads();
    lofs[t] = ex;
    base[t] = atomicAdd(&gcur[t], v);
    __syncthreads();
#pragma unroll
    for (int k = 0; k < 8; ++k) {
        int idx = t + k * PT1_THREADS;
        if (idx < cnt) {
            uint pos = lofs[myb[k]] + myr[k];
            stage[pos] = mys[k];
            sbuck[pos] = (ushort)myb[k];
        }
    }
    __syncthreads();
#pragma unroll
    for (int k = 0; k < 8; ++k) {
        int idx = t + k * PT1_THREADS;
        if (idx < cnt) {
            uint b = sbuck[idx];
            packed1[base[b] + ((uint)idx - lofs[b])] = stage[idx];
        }
    }
}

// ---- per-bucket: node degrees -> dis, and per-(d,s) counts (no global atomics) ----
__global__ void k_deg2b(const uint* __restrict__ packed1, const uint* __restrict__ bbase,
                        float* __restrict__ dis, uint* __restrict__ count2, int N) {
    __shared__ uint c[512];
    __shared__ uint sh[NS];
    int d = blockIdx.x, t = threadIdx.x;  // 256 threads
    for (int i = t; i < 512; i += 256) c[i] = 0;
    if (t < NS) sh[t] = 0;
    __syncthreads();
    uint beg = bbase[d], end = bbase[d + 1];
    for (uint e = beg + t; e < end; e += 256) {
        uint v = packed1[e];
        atomicAdd(&c[v >> 19], 1u);
        atomicAdd(&sh[(v & 0x7FFFFu) >> 13], 1u);
    }
    __syncthreads();
    int nodeBase = d << 9;
    for (int i = t; i < 512; i += 256) {
        int node = nodeBase + i;
        if (node < N) dis[node] = rsqrtf((float)(c[i] + 1u));
    }
    if (t < NS) count2[d * NS + t] = sh[t];
}

// ---- scan machinery over count2 (65536 entries, d-major) ----
__global__ void k_bsum(const uint* __restrict__ cnt, int M, uint* __restrict__ bsum) {
    __shared__ uint s[256];
    int t = threadIdx.x;
    int i = blockIdx.x * 256 + t;
    s[t] = (i < M) ? cnt[i] : 0u;
    __syncthreads();
    for (int off = 128; off > 0; off >>= 1) {
        if (t < off) s[t] += s[t + off];
        __syncthreads();
    }
    if (t == 0) bsum[blockIdx.x] = s[0];
}

__global__ void k_scan_bsum(uint* __restrict__ bsum, int nb) {
    __shared__ uint s[256];
    int t = threadIdx.x;
    int c = (nb + 255) / 256;
    int k0 = t * c, k1 = min(k0 + c, nb);
    uint sum = 0;
    for (int k = k0; k < k1; ++k) sum += bsum[k];
    s[t] = sum;
    __syncthreads();
    for (int off = 1; off < 256; off <<= 1) {
        uint x = (t >= off) ? s[t - off] : 0u;
        __syncthreads();
        s[t] += x;
        __syncthreads();
    }
    uint run = s[t] - sum;
    for (int k = k0; k < k1; ++k) {
        uint v = bsum[k];
        bsum[k] = run;
        run += v;
    }
}

__global__ void k_cursor(const uint* __restrict__ cnt, const uint* __restrict__ bsumEx,
                         int M, uint* __restrict__ gcur2) {
    __shared__ uint s[256];
    int t = threadIdx.x;
    int i = blockIdx.x * 256 + t;
    uint v = (i < M) ? cnt[i] : 0u;
    s[t] = v;
    __syncthreads();
    for (int off = 1; off < 256; off <<= 1) {
        uint x = (t >= off) ? s[t - off] : 0u;
        __syncthreads();
        s[t] += x;
        __syncthreads();
    }
    if (i < M) gcur2[i] = bsumEx[blockIdx.x] + s[t] - v;
}

// ---- pass-2: within each dst-bucket, partition by src-super ----
__global__ __launch_bounds__(PT2_THREADS) void k_part2(const uint* __restrict__ packed1, int E,
        const uint* __restrict__ bbase, uint* __restrict__ gcur2, uint* __restrict__ packed2) {
    __shared__ uint stage[PT_TILE];
    __shared__ uint hist[NS], lofs[NS], base[NS];
    int t = threadIdx.x;
    uint start = (uint)blockIdx.x * PT_TILE;
    uint tend = min(start + (uint)PT_TILE, (uint)E);
    // binary search dst-bucket range of this tile (block-uniform)
    int lo = 0, hi = NB;
    while (lo < hi) { int mid = (lo + hi + 1) >> 1; if (bbase[mid] <= start) lo = mid; else hi = mid - 1; }
    int dLo = lo;
    lo = 0; hi = NB;
    uint last = tend - 1;
    while (lo < hi) { int mid = (lo + hi + 1) >> 1; if (bbase[mid] <= last) lo = mid; else hi = mid - 1; }
    int dHi = lo;
    for (int d = dLo; d <= dHi; ++d) {
        uint segLo = max(start, bbase[d]);
        uint segHi = min(tend, bbase[d + 1]);
        if (segHi <= segLo) continue;  // block-uniform condition
        int m = (int)(segHi - segLo);
        if (t < NS) hist[t] = 0;
        __syncthreads();
        uint vv[16], rr[16];
        int nk = 0;
        for (int idx = (int)segLo + t; idx < (int)segHi; idx += PT2_THREADS) {
            uint v = packed1[idx];
            vv[nk] = v;
            rr[nk] = atomicAdd(&hist[(v & 0x7FFFFu) >> 13], 1u);
            ++nk;
        }
        __syncthreads();
        if (t < NS) lofs[t] = hist[t];
        __syncthreads();
        for (int off = 1; off < NS; off <<= 1) {
            uint x = 0;
            if (t < NS && t >= off) x = lofs[t - off];
            __syncthreads();
            if (t < NS) lofs[t] += x;
            __syncthreads();
        }
        if (t < NS) {
            uint inc = lofs[t];
            lofs[t] = inc - hist[t];                       // exclusive
            base[t] = atomicAdd(&gcur2[d * NS + t], hist[t]);
        }
        __syncthreads();
        for (int k = 0; k < nk; ++k) {
            uint v = vv[k];
            stage[lofs[(v & 0x7FFFFu) >> 13] + rr[k]] = v;
        }
        __syncthreads();
        for (int idx = t; idx < m; idx += PT2_THREADS) {
            uint v = stage[idx];
            uint s = (v & 0x7FFFFu) >> 13;
            packed2[base[s] + ((uint)idx - lofs[s])] = v;
        }
        __syncthreads();
    }
}

// ---- layer-1 input transform: A[i,0:15] = x[i,:]@W1, A[i,15]=0 (fp32) ----
__global__ void k_lin_first(const float* __restrict__ x, const float* __restrict__ W,
                            float* __restrict__ A, int N) {
    int i = blockIdx.x * blockDim.x + threadIdx.x;
    if (i >= N) return;
    float in[15];
#pragma unroll
    for (int j = 0; j < 15; ++j) in[j] = x[i * 15 + j];
#pragma unroll
    for (int o = 0; o < 15; ++o) {
        float acc = 0.f;
#pragma unroll
        for (int j = 0; j < 15; ++j) acc = fmaf(in[j], W[j * 15 + o], acc);
        A[i * 16 + o] = acc;
    }
    A[i * 16 + 15] = 0.f;
}

// ---- agg pass 1: fp32 A -> relu(agg+b1) @ W2 -> fp16 B ----
__global__ __launch_bounds__(512) void k_agg_a(const float* __restrict__ A,
        const uint* __restrict__ packed2, const uint* __restrict__ bbase,
        const float* __restrict__ dis, const float* __restrict__ W2,
        const float* __restrict__ b1, __half* __restrict__ B, int N) {
    __shared__ float acc[512 * 16];
    __shared__ float disL[512];
    __shared__ float sW[225];
    __shared__ float sB[15];
    int d = blockIdx.x, t = threadIdx.x;
    int nodeBase = d << 9;
    disL[t] = (nodeBase + t < N) ? dis[nodeBase + t] : 0.f;
    if (t < 225) sW[t] = W2[t];
    if (t < 15) sB[t] = b1[t];
    __syncthreads();
    for (int i = t; i < 512 * 16; i += 512) {
        int node = nodeBase + (i >> 4);
        float dv = disL[i >> 4];
        acc[i] = (node < N) ? A[node * 16 + (i & 15)] * dv * dv : 0.f;
    }
    __syncthreads();
    uint beg = bbase[d], end = bbase[d + 1];
    int j = t & 15;
    uint e = beg + (t >> 4);
    for (; e + 96 < end; e += 128) {
        uint v0 = packed2[e], v1 = packed2[e + 32], v2 = packed2[e + 64], v3 = packed2[e + 96];
        uint s0 = v0 & 0x7FFFFu, s1 = v1 & 0x7FFFFu, s2 = v2 & 0x7FFFFu, s3 = v3 & 0x7FFFFu;
        float w0 = dis[s0] * disL[v0 >> 19], w1 = dis[s1] * disL[v1 >> 19];
        float w2 = dis[s2] * disL[v2 >> 19], w3 = dis[s3] * disL[v3 >> 19];
        float h0 = A[s0 * 16 + j], h1 = A[s1 * 16 + j];
        float h2 = A[s2 * 16 + j], h3 = A[s3 * 16 + j];
        atomicAdd(&acc[(v0 >> 19) * 16 + j], h0 * w0);
        atomicAdd(&acc[(v1 >> 19) * 16 + j], h1 * w1);
        atomicAdd(&acc[(v2 >> 19) * 16 + j], h2 * w2);
        atomicAdd(&acc[(v3 >> 19) * 16 + j], h3 * w3);
    }
    for (; e < end; e += 32) {
        uint v = packed2[e];
        uint s = v & 0x7FFFFu;
        atomicAdd(&acc[(v >> 19) * 16 + j], A[s * 16 + j] * dis[s] * disL[v >> 19]);
    }
    __syncthreads();
    for (int i = t >> 4; i < 512; i += 32) {
        int node = nodeBase + i;
        if (node >= N) continue;
        float o = 0.f;
        if (j < 15) {
#pragma unroll
            for (int k = 0; k < 15; ++k) {
                float hk = acc[i * 16 + k] + sB[k];
                hk = hk > 0.f ? hk : 0.f;
                o = fmaf(hk, sW[k * 15 + j], o);
            }
        }
        B[node * 16 + j] = __float2half(j < 15 ? o : 0.f);
    }
}

// ---- agg pass 2: fp16 B -> relu(agg+b2) @ W3 -> fp16 C (4-wide) ----
__global__ __launch_bounds__(512) void k_agg_b(const __half* __restrict__ Bh,
        const uint* __restrict__ packed2, const uint* __restrict__ bbase,
        const float* __restrict__ dis, const float* __restrict__ W3,
        const float* __restrict__ b2, __half* __restrict__ C, int N) {
    __shared__ float acc[512 * 16];
    __shared__ float disL[512];
    __shared__ float sW[60];
    __shared__ float sB[15];
    int d = blockIdx.x, t = threadIdx.x;
    int nodeBase = d << 9;
    disL[t] = (nodeBase + t < N) ? dis[nodeBase + t] : 0.f;
    if (t < 60) sW[t] = W3[t];
    if (t < 15) sB[t] = b2[t];
    __syncthreads();
    for (int i = t; i < 512 * 16; i += 512) {
        int node = nodeBase + (i >> 4);
        float dv = disL[i >> 4];
        acc[i] = (node < N) ? __half2float(Bh[node * 16 + (i & 15)]) * dv * dv : 0.f;
    }
    __syncthreads();
    uint beg = bbase[d], end = bbase[d + 1];
    int j = t & 15;
    uint e = beg + (t >> 4);
    for (; e + 96 < end; e += 128) {
        uint v0 = packed2[e], v1 = packed2[e + 32], v2 = packed2[e + 64], v3 = packed2[e + 96];
        uint s0 = v0 & 0x7FFFFu, s1 = v1 & 0x7FFFFu, s2 = v2 & 0x7FFFFu, s3 = v3 & 0x7FFFFu;
        float w0 = dis[s0] * disL[v0 >> 19], w1 = dis[s1] * disL[v1 >> 19];
        float w2 = dis[s2] * disL[v2 >> 19], w3 = dis[s3] * disL[v3 >> 19];
        float h0 = __half2float(Bh[s0 * 16 + j]), h1 = __half2float(Bh[s1 * 16 + j]);
        float h2 = __half2float(Bh[s2 * 16 + j]), h3 = __half2float(Bh[s3 * 16 + j]);
        atomicAdd(&acc[(v0 >> 19) * 16 + j], h0 * w0);
        atomicAdd(&acc[(v1 >> 19) * 16 + j], h1 * w1);
        atomicAdd(&acc[(v2 >> 19) * 16 + j], h2 * w2);
        atomicAdd(&acc[(v3 >> 19) * 16 + j], h3 * w3);
    }
    for (; e < end; e += 32) {
        uint v = packed2[e];
        uint s = v & 0x7FFFFu;
        atomicAdd(&acc[(v >> 19) * 16 + j],
                  __half2float(Bh[s * 16 + j]) * dis[s] * disL[v >> 19]);
    }
    __syncthreads();
    for (int i = t >> 4; i < 512; i += 32) {
        int node = nodeBase + i;
        if (node >= N || j >= 4) continue;
        float o = 0.f;
#pragma unroll
        for (int k = 0; k < 15; ++k) {
            float hk = acc[i * 16 + k] + sB[k];
            hk = hk > 0.f ? hk : 0.f;
            o = fmaf(hk, sW[k * 4 + j], o);
        }
        C[node * 4 + j] = __float2half(o);
    }
}

// ---- agg pass 3: fp16 C -> out fp32 (+b3) ----
__global__ __launch_bounds__(512) void k_agg_c(const __half* __restrict__ C,
        const uint* __restrict__ packed2, const uint* __restrict__ bbase,
        const float* __restrict__ dis, const float* __restrict__ b3,
        float* __restrict__ out, int N) {
    __shared__ float acc[512 * 4];
    __shared__ float disL[512];
    int d = blockIdx.x, t = threadIdx.x;
    int nodeBase = d << 9;
    disL[t] = (nodeBase + t < N) ? dis[nodeBase + t] : 0.f;
    __syncthreads();
    for (int i = t; i < 512 * 4; i += 512) {
        int node = nodeBase + (i >> 2);
        float dv = disL[i >> 2];
        acc[i] = (node < N) ? __half2float(C[node * 4 + (i & 3)]) * dv * dv : 0.f;
    }
    __syncthreads();
    uint beg = bbase[d], end = bbase[d + 1];
    int j = t & 3;
    uint e = beg + (t >> 2);
    for (; e + 384 < end; e += 512) {
        uint v0 = packed2[e], v1 = packed2[e + 128], v2 = packed2[e + 256], v3 = packed2[e + 384];
        uint s0 = v0 & 0x7FFFFu, s1 = v1 & 0x7FFFFu, s2 = v2 & 0x7FFFFu, s3 = v3 & 0x7FFFFu;
        float w0 = dis[s0] * disL[v0 >> 19], w1 = dis[s1] * disL[v1 >> 19];
        float w2 = dis[s2] * disL[v2 >> 19], w3 = dis[s3] * disL[v3 >> 19];
        float h0 = __half2float(C[s0 * 4 + j]), h1 = __half2float(C[s1 * 4 + j]);
        float h2 = __half2float(C[s2 * 4 + j]), h3 = __half2float(C[s3 * 4 + j]);
        atomicAdd(&acc[(v0 >> 19) * 4 + j], h0 * w0);
        atomicAdd(&acc[(v1 >> 19) * 4 + j], h1 * w1);
        atomicAdd(&acc[(v2 >> 19) * 4 + j], h2 * w2);
        atomicAdd(&acc[(v3 >> 19) * 4 + j], h3 * w3);
    }
    for (; e < end; e += 128) {
        uint v = packed2[e];
        uint s = v & 0x7FFFFu;
        atomicAdd(&acc[(v >> 19) * 4 + j],
                  __half2float(C[s * 4 + j]) * dis[s] * disL[v >> 19]);
    }
    __syncthreads();
    for (int i = t >> 2; i < 512; i += 128) {
        int node = nodeBase + i;
        if (node < N) out[node * 4 + j] = acc[i * 4 + j] + b3[j];
    }
}

extern "C" void kernel_launch(void* const* d_in, const int* in_sizes, int n_in,
                              void* d_out, int out_size, void* d_ws, size_t ws_size,
                              hipStream_t stream) {
    const float* x  = (const float*)d_in[0];
    const int*   ei = (const int*)d_in[1];
    const float* W1 = (const float*)d_in[3];
    const float* b1 = (const float*)d_in[4];
    const float* W2 = (const float*)d_in[5];
    const float* b2 = (const float*)d_in[6];
    const float* W3 = (const float*)d_in[7];
    const float* b3 = (const float*)d_in[8];
    float* out = (float*)d_out;

    const int N = in_sizes[0] / 15;
    const int E = in_sizes[1] / 2;
    const int* src = ei;
    const int* dst = ei + E;
    const int nBk = (N + 511) >> 9;           // live dst-buckets (977)
    const int M2 = NB * NS;                   // 65536 (d,s) keys

    char* ws = (char*)d_ws;
    auto align = [](size_t v) { return (v + 255) & ~(size_t)255; };
    size_t off = 0;
    uint* bcnt   = (uint*)(ws + off); off += align((size_t)NB * 4);
    uint* bbase  = (uint*)(ws + off); off += align((size_t)(NB + 1) * 4);
    uint* gcur   = (uint*)(ws + off); off += align((size_t)NB * 4);
    uint* count2 = (uint*)(ws + off); off += align((size_t)M2 * 4);
    uint* bsum2  = (uint*)(ws + off); off += align((size_t)256 * 4);
    uint* gcur2  = (uint*)(ws + off); off += align((size_t)M2 * 4);
    float* dis   = (float*)(ws + off); off += align((size_t)N * 4);
    uint* packed2 = (uint*)(ws + off); off += align((size_t)E * 4);
    // slabX: packed1 (E*4 B) overlaid later by A(fp32)+B(fp16)+C(fp16)
    char* slabX = ws + off;
    uint* packed1 = (uint*)slabX;
    float*  A  = (float*)slabX;
    __half* Bh = (__half*)(slabX + align((size_t)N * 16 * 4));
    __half* C  = (__half*)(slabX + align((size_t)N * 16 * 4) + align((size_t)N * 16 * 2));

    const int nTiles = (E + PT_TILE - 1) / PT_TILE;

    // CSR-free build: bucket by dst, then by src-super within
    hipMemsetAsync(bcnt, 0, (size_t)NB * 4, stream);
    hipMemsetAsync(count2, 0, (size_t)M2 * 4, stream);
    k_hist<<<2048, 256, 0, stream>>>(dst, E, bcnt);
    k_scan_buckets<<<1, NB, 0, stream>>>(bcnt, bbase, gcur);
    k_part<<<nTiles, PT1_THREADS, 0, stream>>>(src, dst, E, gcur, packed1);
    k_deg2b<<<nBk, 256, 0, stream>>>(packed1, bbase, dis, count2, N);
    k_bsum<<<M2 / 256, 256, 0, stream>>>(count2, M2, bsum2);
    k_scan_bsum<<<1, 256, 0, stream>>>(bsum2, M2 / 256);
    k_cursor<<<M2 / 256, 256, 0, stream>>>(count2, bsum2, M2, gcur2);
    k_part2<<<nTiles, PT2_THREADS, 0, stream>>>(packed1, E, bbase, gcur2, packed2);
    // packed1 dead; slabX becomes A/B/C

    k_lin_first<<<(N + 255) / 256, 256, 0, stream>>>(x, W1, A, N);
    k_agg_a<<<nBk, 512, 0, stream>>>(A, packed2, bbase, dis, W2, b1, Bh, N);
    k_agg_b<<<nBk, 512, 0, stream>>>(Bh, packed2, bbase, dis, W3, b2, C, N);
    k_agg_c<<<nBk, 512, 0, stream>>>(C, packed2, bbase, dis, b3, out, N);
}

// Round 5
// 1162.211 us; speedup vs baseline: 3.0171x; 3.0171x over previous
//
#include <hip/hip_runtime.h>
#include <hip/hip_fp16.h>

// GCN 3-layer forward. R5 = R3 CSR-pull structure (proven) + request-count cuts:
//  - rows pre-scaled by dis[src] => no per-edge dis gather, no per-edge mults
//    (Sum_e dis_s dis_d h_s = dis_d * Sum_e (dis_s h_s))
//  - edge lists padded to 4 (sentinel zero-row N) => int4 srcS loads, 4 gathers in flight
//  - B', C' fp16 (R4 validated numerics); C' = 4MB -> per-XCD-L2 resident
// R4 lesson: fancy locality partition was latency-bound (585 GB/s, 3.8 blk/CU). Reverted.

typedef unsigned int uint;
typedef unsigned short ushort;

#define NB 512            // dst buckets (dst >> 10), 1024 nodes each
#define PT_THREADS 512
#define PT_TILE 8192

// ---- bucket histogram ----
__global__ void k_hist(const int* __restrict__ dst, int E, uint* __restrict__ bcnt) {
    __shared__ uint h[NB];
    int t = threadIdx.x;
    for (int i = t; i < NB; i += 256) h[i] = 0;
    __syncthreads();
    for (long long e = (long long)blockIdx.x * 256 + t; e < E; e += (long long)gridDim.x * 256)
        atomicAdd(&h[((uint)dst[e]) >> 10], 1u);
    __syncthreads();
    for (int i = t; i < NB; i += 256) if (h[i]) atomicAdd(&bcnt[i], h[i]);
}

__global__ void k_scan_buckets(const uint* __restrict__ bcnt, uint* __restrict__ bbase,
                               uint* __restrict__ gcur) {
    __shared__ uint s[NB];
    int t = threadIdx.x;
    uint v = bcnt[t];
    s[t] = v;
    __syncthreads();
    for (int off = 1; off < NB; off <<= 1) {
        uint x = (t >= off) ? s[t - off] : 0u;
        __syncthreads();
        s[t] += x;
        __syncthreads();
    }
    uint ex = s[t] - v;
    bbase[t] = ex;
    gcur[t] = ex;
    if (t == NB - 1) bbase[NB] = s[t];
}

// ---- LDS-staged partition: edges -> bucketed (packed src | dstLocal<<19) ----
__global__ __launch_bounds__(PT_THREADS) void k_part(const int* __restrict__ src,
                                                     const int* __restrict__ dst, int E,
                                                     uint* __restrict__ gcur,
                                                     uint* __restrict__ bucketed) {
    __shared__ uint stage[PT_TILE];
    __shared__ ushort sbuck[PT_TILE];
    __shared__ uint hist[NB], lofs[NB], base[NB];
    int t = threadIdx.x;
    long long start = (long long)blockIdx.x * PT_TILE;
    int cnt = (int)min((long long)PT_TILE, (long long)E - start);

    hist[t] = 0;
    __syncthreads();
    uint myb[16], myr[16], mys[16];
#pragma unroll
    for (int k = 0; k < 16; ++k) {
        int idx = t + k * PT_THREADS;
        if (idx < cnt) {
            uint d = (uint)dst[start + idx];
            uint s = (uint)src[start + idx];
            uint b = d >> 10;
            myb[k] = b;
            mys[k] = s | ((d & 1023u) << 19);
            myr[k] = atomicAdd(&hist[b], 1u);
        }
    }
    __syncthreads();
    uint v = hist[t];
    lofs[t] = v;
    __syncthreads();
    for (int off = 1; off < NB; off <<= 1) {
        uint x = (t >= off) ? lofs[t - off] : 0u;
        __syncthreads();
        lofs[t] += x;
        __syncthreads();
    }
    uint ex = lofs[t] - v;
    __syncthreads();
    lofs[t] = ex;
    base[t] = atomicAdd(&gcur[t], v);
    __syncthreads();
#pragma unroll
    for (int k = 0; k < 16; ++k) {
        int idx = t + k * PT_THREADS;
        if (idx < cnt) {
            uint pos = lofs[myb[k]] + myr[k];
            stage[pos] = mys[k];
            sbuck[pos] = (ushort)myb[k];
        }
    }
    __syncthreads();
#pragma unroll
    for (int k = 0; k < 16; ++k) {
        int idx = t + k * PT_THREADS;
        if (idx < cnt) {
            uint b = sbuck[idx];
            bucketed[base[b] + ((uint)idx - lofs[b])] = stage[idx];
        }
    }
}

// ---- per-bucket degree -> padded counts + dis (LDS counters) ----
__global__ void k_deg2(const uint* __restrict__ bucketed, const uint* __restrict__ bbase,
                       uint* __restrict__ cntPad, float* __restrict__ dis, int N) {
    __shared__ uint c[1024];
    int b = blockIdx.x, t = threadIdx.x;
    for (int i = t; i < 1024; i += 256) c[i] = 0;
    __syncthreads();
    uint beg = bbase[b], end = bbase[b + 1];
    for (uint e = beg + t; e < end; e += 256) atomicAdd(&c[bucketed[e] >> 19], 1u);
    __syncthreads();
    int nodeBase = b << 10;
    for (int i = t; i < 1024; i += 256) {
        int node = nodeBase + i;
        if (node < N) {
            uint cc = c[i];
            cntPad[node] = (cc + 3u) & ~3u;          // pad to multiple of 4
            dis[node] = rsqrtf((float)(cc + 1u));    // +1 self-loop
        }
    }
}

// ---- node-level scan machinery (over padded counts) ----
__global__ void k_bsum(const uint* __restrict__ cnt, int N, uint* __restrict__ bsum) {
    __shared__ uint s[256];
    int t = threadIdx.x;
    int i = blockIdx.x * 256 + t;
    s[t] = (i < N) ? cnt[i] : 0u;
    __syncthreads();
    for (int off = 128; off > 0; off >>= 1) {
        if (t < off) s[t] += s[t + off];
        __syncthreads();
    }
    if (t == 0) bsum[blockIdx.x] = s[0];
}

__global__ void k_scan_bsum(uint* __restrict__ bsum, int nb) {
    __shared__ uint s[256];
    int t = threadIdx.x;
    int c = (nb + 255) / 256;
    int k0 = t * c, k1 = min(k0 + c, nb);
    uint sum = 0;
    for (int k = k0; k < k1; ++k) sum += bsum[k];
    s[t] = sum;
    __syncthreads();
    for (int off = 1; off < 256; off <<= 1) {
        uint x = (t >= off) ? s[t - off] : 0u;
        __syncthreads();
        s[t] += x;
        __syncthreads();
    }
    uint run = s[t] - sum;
    for (int k = k0; k < k1; ++k) {
        uint v = bsum[k];
        bsum[k] = run;
        run += v;
    }
}

__global__ void k_rowptr(const uint* __restrict__ cnt, const uint* __restrict__ bsumEx,
                         int N, uint* __restrict__ rowp) {
    __shared__ uint s[256];
    int t = threadIdx.x;
    int i = blockIdx.x * 256 + t;
    uint v = (i < N) ? cnt[i] : 0u;
    s[t] = v;
    __syncthreads();
    for (int off = 1; off < 256; off <<= 1) {
        uint x = (t >= off) ? s[t - off] : 0u;
        __syncthreads();
        s[t] += x;
        __syncthreads();
    }
    if (i < N) {
        uint rp = bsumEx[blockIdx.x] + s[t] - v;   // multiple of 4 by construction
        rowp[i] = rp;
        if (i == N - 1) rowp[N] = rp + v;
    }
}

// ---- per-bucket CSR fill + sentinel padding ----
__global__ void k_fill2(const uint* __restrict__ bucketed, const uint* __restrict__ bbase,
                        const uint* __restrict__ rowp, int* __restrict__ srcS, int N) {
    __shared__ uint cur[1024];
    int b = blockIdx.x, t = threadIdx.x;
    int nodeBase = b << 10;
    for (int i = t; i < 1024; i += 256) {
        int node = nodeBase + i;
        cur[i] = (node < N) ? rowp[node] : 0u;
    }
    __syncthreads();
    uint beg = bbase[b], end = bbase[b + 1];
    for (uint e = beg + t; e < end; e += 256) {
        uint v = bucketed[e];
        uint pos = atomicAdd(&cur[v >> 19], 1u);
        srcS[pos] = (int)(v & 0x7ffffu);
    }
    __syncthreads();
    for (int i = t; i < 1024; i += 256) {
        int node = nodeBase + i;
        if (node >= N) continue;
        uint ce = cur[i];
        uint pe = (ce + 3u) & ~3u;
        for (uint p = ce; p < pe; ++p) srcS[p] = N;   // sentinel zero-row
    }
}

// ---- layer-1: A'[i,0:15] = (x[i,:]@W1) * dis[i], A'[i,15]=0 ----
__global__ void k_lin_first(const float* __restrict__ x, const float* __restrict__ W,
                            const float* __restrict__ dis, float* __restrict__ A, int N) {
    int i = blockIdx.x * blockDim.x + threadIdx.x;
    if (i >= N) return;
    float in[15];
#pragma unroll
    for (int j = 0; j < 15; ++j) in[j] = x[i * 15 + j];
    float di = dis[i];
#pragma unroll
    for (int o = 0; o < 15; ++o) {
        float acc = 0.f;
#pragma unroll
        for (int j = 0; j < 15; ++j) acc = fmaf(in[j], W[j * 15 + o], acc);
        A[i * 16 + o] = acc * di;
    }
    A[i * 16 + 15] = 0.f;
}

// ---- pull 1: fp32 A' -> relu(dis*Sum + b1) @ W2 -> fp16 B' (pre-scaled) ----
__global__ void k_pull1(const float* __restrict__ Ap, const int* __restrict__ srcS,
                        const uint* __restrict__ rowp, const float* __restrict__ dis,
                        const float* __restrict__ W2, const float* __restrict__ b1,
                        __half* __restrict__ Bp, int N) {
    __shared__ float v[16 * 16];
    int tid = blockIdx.x * blockDim.x + threadIdx.x;
    int node = tid >> 4;
    int j = tid & 15;
    int local = threadIdx.x >> 4;
    bool valid = node < N;
    float di = 0.f;
    if (valid) {
        di = dis[node];
        float acc = Ap[node * 16 + j];                 // self term (already dis_i-scaled)
        uint e = rowp[node], rend = rowp[node + 1];    // length % 4 == 0, e % 4 == 0
        for (; e < rend; e += 4) {
            int4 s4 = *(const int4*)(srcS + e);        // 16B-aligned
            float h0 = Ap[s4.x * 16 + j], h1 = Ap[s4.y * 16 + j];
            float h2 = Ap[s4.z * 16 + j], h3 = Ap[s4.w * 16 + j];
            acc += (h0 + h1) + (h2 + h3);
        }
        float val = (j < 15) ? (acc * di + b1[j]) : 0.f;
        v[local * 16 + j] = val > 0.f ? val : 0.f;
    } else {
        v[local * 16 + j] = 0.f;
    }
    __syncthreads();
    if (valid) {
        float o = 0.f;
        if (j < 15) {
#pragma unroll
            for (int k = 0; k < 15; ++k) o = fmaf(v[local * 16 + k], W2[k * 15 + j], o);
        }
        Bp[node * 16 + j] = __float2half((j < 15 ? o : 0.f) * di);   // pre-scale for next layer
    }
}

// ---- pull 2: fp16 B' -> relu(dis*Sum + b2) @ W3 -> fp16 C' (pre-scaled, 4-wide) ----
__global__ void k_pull2(const __half* __restrict__ Bp, const int* __restrict__ srcS,
                        const uint* __restrict__ rowp, const float* __restrict__ dis,
                        const float* __restrict__ W3, const float* __restrict__ b2,
                        __half* __restrict__ Cp, int N) {
    __shared__ float v[16 * 16];
    int tid = blockIdx.x * blockDim.x + threadIdx.x;
    int node = tid >> 4;
    int j = tid & 15;
    int local = threadIdx.x >> 4;
    bool valid = node < N;
    float di = 0.f;
    if (valid) {
        di = dis[node];
        float acc = __half2float(Bp[node * 16 + j]);
        uint e = rowp[node], rend = rowp[node + 1];
        for (; e < rend; e += 4) {
            int4 s4 = *(const int4*)(srcS + e);
            float h0 = __half2float(Bp[s4.x * 16 + j]);
            float h1 = __half2float(Bp[s4.y * 16 + j]);
            float h2 = __half2float(Bp[s4.z * 16 + j]);
            float h3 = __half2float(Bp[s4.w * 16 + j]);
            acc += (h0 + h1) + (h2 + h3);
        }
        float val = (j < 15) ? (acc * di + b2[j]) : 0.f;
        v[local * 16 + j] = val > 0.f ? val : 0.f;
    } else {
        v[local * 16 + j] = 0.f;
    }
    __syncthreads();
    if (valid && j < 4) {
        float o = 0.f;
#pragma unroll
        for (int k = 0; k < 15; ++k) o = fmaf(v[local * 16 + k], W3[k * 4 + j], o);
        Cp[node * 4 + j] = __float2half(o * di);
    }
}

// ---- pull 3: fp16 C' (4MB, L2-resident) -> out fp32 ----
__global__ void k_pull3(const __half* __restrict__ Cp, const int* __restrict__ srcS,
                        const uint* __restrict__ rowp, const float* __restrict__ dis,
                        const float* __restrict__ b3, float* __restrict__ out, int N) {
    int tid = blockIdx.x * blockDim.x + threadIdx.x;
    int node = tid >> 2;
    int j = tid & 3;
    if (node >= N) return;
    float acc = __half2float(Cp[node * 4 + j]);
    uint e = rowp[node], rend = rowp[node + 1];
    for (; e < rend; e += 4) {
        int4 s4 = *(const int4*)(srcS + e);
        float h0 = __half2float(Cp[s4.x * 4 + j]);
        float h1 = __half2float(Cp[s4.y * 4 + j]);
        float h2 = __half2float(Cp[s4.z * 4 + j]);
        float h3 = __half2float(Cp[s4.w * 4 + j]);
        acc += (h0 + h1) + (h2 + h3);
    }
    out[(size_t)node * 4 + j] = acc * dis[node] + b3[j];
}

extern "C" void kernel_launch(void* const* d_in, const int* in_sizes, int n_in,
                              void* d_out, int out_size, void* d_ws, size_t ws_size,
                              hipStream_t stream) {
    const float* x  = (const float*)d_in[0];
    const int*   ei = (const int*)d_in[1];
    const float* W1 = (const float*)d_in[3];
    const float* b1 = (const float*)d_in[4];
    const float* W2 = (const float*)d_in[5];
    const float* b2 = (const float*)d_in[6];
    const float* W3 = (const float*)d_in[7];
    const float* b3 = (const float*)d_in[8];
    float* out = (float*)d_out;

    const int N = in_sizes[0] / 15;
    const int E = in_sizes[1] / 2;
    const int* src = ei;
    const int* dst = ei + E;
    const int nb  = (N + 255) / 256;
    const int NBr = (N + 1023) >> 10;

    char* ws = (char*)d_ws;
    auto align = [](size_t v) { return (v + 255) & ~(size_t)255; };
    size_t off = 0;
    uint* cnt   = (uint*)(ws + off); off += align((size_t)N * 4);
    uint* rowp  = (uint*)(ws + off); off += align((size_t)(N + 1) * 4);
    uint* bsum  = (uint*)(ws + off); off += align((size_t)nb * 4);
    float* dis  = (float*)(ws + off); off += align((size_t)N * 4);
    uint* bcnt  = (uint*)(ws + off); off += align((size_t)NB * 4);
    uint* bbase = (uint*)(ws + off); off += align((size_t)(NB + 1) * 4);
    uint* gcur  = (uint*)(ws + off); off += align((size_t)NB * 4);
    int*  srcS  = (int*)(ws + off);  off += align(((size_t)E + 3 * (size_t)N + 64) * 4);
    // slabY: bucketed (64MB) dead after k_fill2, overlaid by B'(fp16)+C'(fp16)
    char* slabY = ws + off;
    uint*   bucketed = (uint*)slabY;
    __half* Bp = (__half*)slabY;
    __half* Cp = (__half*)(slabY + align((size_t)(N + 1) * 16 * 2));
    off += align(max((size_t)E * 4,
                     align((size_t)(N + 1) * 16 * 2) + (size_t)(N + 1) * 4 * 2));
    float* Ap = (float*)(ws + off);  // (N+1) x 16 fp32

    const int nTiles = (E + PT_TILE - 1) / PT_TILE;
    const int gN16 = (int)(((long long)N * 16 + 255) / 256);
    const int gN4  = (int)(((long long)N * 4 + 255) / 256);

    // CSR build (bucketed, padded to 4)
    hipMemsetAsync(bcnt, 0, (size_t)NB * 4, stream);
    k_hist<<<2048, 256, 0, stream>>>(dst, E, bcnt);
    k_scan_buckets<<<1, NB, 0, stream>>>(bcnt, bbase, gcur);
    k_part<<<nTiles, PT_THREADS, 0, stream>>>(src, dst, E, gcur, bucketed);
    k_deg2<<<NBr, 256, 0, stream>>>(bucketed, bbase, cnt, dis, N);
    k_bsum<<<nb, 256, 0, stream>>>(cnt, N, bsum);
    k_scan_bsum<<<1, 256, 0, stream>>>(bsum, nb);
    k_rowptr<<<nb, 256, 0, stream>>>(cnt, bsum, N, rowp);
    k_fill2<<<NBr, 256, 0, stream>>>(bucketed, bbase, rowp, srcS, N);
    // bucketed dead -> slabY becomes B'/C'

    // sentinel zero-rows (row N) — ws is re-poisoned each call, so do this every time
    k_lin_first<<<nb, 256, 0, stream>>>(x, W1, dis, Ap, N);
    hipMemsetAsync(Ap + (size_t)N * 16, 0, 16 * 4, stream);
    hipMemsetAsync(Bp + (size_t)N * 16, 0, 16 * 2, stream);
    hipMemsetAsync(Cp + (size_t)N * 4, 0, 4 * 2, stream);

    k_pull1<<<gN16, 256, 0, stream>>>(Ap, srcS, rowp, dis, W2, b1, Bp, N);
    k_pull2<<<gN16, 256, 0, stream>>>(Bp, srcS, rowp, dis, W3, b2, Cp, N);
    k_pull3<<<gN4, 256, 0, stream>>>(Cp, srcS, rowp, dis, b3, out, N);
}